// Round 9
// baseline (1750.763 us; speedup 1.0000x reference)
//
#include <hip/hip_runtime.h>
#include <math.h>

#define RANK 64
#define D_DIM 320          // ENT_COMPS * RANK
#define K_DIM 640          // 2 * D_DIM
#define N_ENT 80000
#define B_Q 2000
#define M_PAD 2048         // B_Q padded (zero rows 2000..2047)
#define NT32 20            // K_DIM / 32
#define SCALE_F 0.125f     // 1/sqrt(64)
#define EPS_F 1e-9f

// d_out layout (floats)
#define OFF_SCORES 0ull
#define OFF_REG0 160000000ull
#define OFF_REG1 160640000ull
#define OFF_REG2 161280000ull
#define OFF_REG3 161920000ull
#define OFF_REG4 162048000ull

typedef __attribute__((ext_vector_type(8))) short short8v;   // 8 bf16 (4 VGPRs)
typedef __attribute__((ext_vector_type(4))) float floatx4;

typedef __attribute__((address_space(1))) const unsigned int gu32;
typedef __attribute__((address_space(3))) unsigned int lu32;

#define VMCNT0() asm volatile("s_waitcnt vmcnt(0)" ::: "memory")
#define LGKM0()  asm volatile("s_waitcnt lgkmcnt(0)" ::: "memory")

static __device__ __forceinline__ unsigned short f2bf(float f) {
    union { float f; unsigned int u; } a; a.f = f;
    unsigned int u = a.u;
    u += 0x7FFFu + ((u >> 16) & 1u);   // RNE (finite inputs only)
    return (unsigned short)(u >> 16);
}

// ---------------------------------------------------------------------------
// Prep body: query row b, lane 0..63. Writes X row (bf16) + reg outputs.
// ---------------------------------------------------------------------------
static __device__ __forceinline__ void prep_row(
    int b, int lane,
    const int* __restrict__ q,
    const float* __restrict__ ent,
    const float* __restrict__ rrot_t,
    const float* __restrict__ rboost_t,
    const float* __restrict__ atten_t,
    const float* __restrict__ aux_t,
    unsigned short* __restrict__ X,
    float* __restrict__ out)
{
    unsigned short* Xrow = X + (size_t)b * K_DIM;

    if (b >= B_Q) {  // zero pad rows so MFMA tiles read clean zeros
        #pragma unroll
        for (int c = 0; c < 10; c++) Xrow[lane * 10 + c] = 0;
        return;
    }

    int h = q[3 * b + 0];
    int r = q[3 * b + 1];
    int t = q[3 * b + 2];

    const float* eh = ent + (size_t)h * K_DIM;
    const float* et = ent + (size_t)t * K_DIM;

    float4 rv = *(const float4*)(rrot_t + (size_t)r * 256 + lane * 4);
    float4 bv = *(const float4*)(rboost_t + (size_t)r * 256 + lane * 4);

    const float* xr = eh + lane * 5;
    float x0 = xr[0], x1 = xr[1], x2 = xr[2], x3 = xr[3], x4 = xr[4];

    float rr2 = rv.x * rv.x + rv.y * rv.y + rv.z * rv.z + rv.w * rv.w;
    float rb2 = bv.x * bv.x + bv.y * bv.y + bv.z * bv.z + bv.w * bv.w;

    // rotate
    float qinv = 1.0f / sqrtf(rr2 + EPS_F);
    float qw = rv.x * qinv, qx = rv.y * qinv, qy = rv.z * qinv, qz = rv.w * qinv;
    float pw = x1, px = x2, py = x3, pz = x4;
    float rot[5];
    rot[0] = x0;
    rot[1] = qw * pw - qx * px - qy * py - qz * pz;
    rot[2] = qw * px + qx * pw + qy * pz - qz * py;
    rot[3] = qw * py - qx * pz + qy * pw + qz * px;
    rot[4] = qw * pz + qx * py - qy * px + qz * pw;

    // boost
    float vn2 = fminf(fmaxf(rb2, 0.0f), 0.999f);
    float sq = sqrtf(1.0f - vn2);
    float gamma = 1.0f / sq;
    float gm1 = vn2 / (sq * (1.0f + sq));  // gamma-1 without cancellation
    float vs = bv.x * x1 + bv.y * x2 + bv.z * x3 + bv.w * x4;
    float boo[5];
    boo[0] = gamma * (x0 + vs);
    float coef = gamma * x0 + gm1 * vs / (vn2 + EPS_F);
    boo[1] = x1 + coef * bv.x;
    boo[2] = x2 + coef * bv.y;
    boo[3] = x3 + coef * bv.z;
    boo[4] = x4 + coef * bv.w;

    // attention
    const float* at = atten_t + (size_t)r * D_DIM + lane * 5;
    float w0 = at[0] * rot[0] + at[1] * rot[1] + at[2] * rot[2] + at[3] * rot[3] + at[4] * rot[4];
    float w1 = at[0] * boo[0] + at[1] * boo[1] + at[2] * boo[2] + at[3] * boo[3] + at[4] * boo[4];
    #pragma unroll
    for (int off = 32; off; off >>= 1) {
        w0 += __shfl_xor(w0, off);
        w1 += __shfl_xor(w1, off);
    }
    w0 *= SCALE_F;
    w1 *= SCALE_F;
    float mx = fmaxf(w0, w1);
    float e0 = expf(w0 - mx), e1 = expf(w1 - mx);
    float inv = 1.0f / (e0 + e1);
    float wt0 = e0 * inv, wt1 = e1 * inv;

    const float* a0p = aux_t + (size_t)r * 640 + lane * 5;
    const float* a1p = a0p + D_DIM;
    float xre[5] = {x0, x1, x2, x3, x4};

    #pragma unroll
    for (int c = 0; c < 5; c++) {
        int d = lane * 5 + c;
        float lhs = wt0 * rot[c] + wt1 * boo[c];
        float im = eh[D_DIM + d];
        float a0 = a0p[c], a1 = a1p[c];
        Xrow[d]         = f2bf(lhs * a0 - im * a1);
        Xrow[D_DIM + d] = f2bf(lhs * a1 + im * a0);
        out[OFF_REG0 + (size_t)b * D_DIM + d] = sqrtf(xre[c] * xre[c] + im * im);
        out[OFF_REG1 + (size_t)b * D_DIM + d] = sqrtf(a0 * a0 + a1 * a1);
        float tre = et[d], tim = et[D_DIM + d];
        out[OFF_REG2 + (size_t)b * D_DIM + d] = sqrtf(tre * tre + tim * tim) * (1.0f / 3.0f);
    }
    out[OFF_REG3 + (size_t)b * RANK + lane] = sqrtf(rr2);
    out[OFF_REG4 + (size_t)b * RANK + lane] = sqrtf(rb2);
}

// ---------------------------------------------------------------------------
// Fused prep + E conversion (R7-verified).
// ---------------------------------------------------------------------------
#define PREP_BLKS 512
#define CONV_BLKS 2048
__global__ __launch_bounds__(256) void prepconv_kernel(
    const int* __restrict__ q,
    const float* __restrict__ ent,
    const float* __restrict__ rrot_t,
    const float* __restrict__ rboost_t,
    const float* __restrict__ atten_t,
    const float* __restrict__ aux_t,
    unsigned short* __restrict__ X,
    unsigned short* __restrict__ Eb,
    float* __restrict__ out)
{
    if (blockIdx.x < PREP_BLKS) {
        int b = blockIdx.x * 4 + (threadIdx.x >> 6);   // 0..2047
        prep_row(b, threadIdx.x & 63, q, ent, rrot_t, rboost_t, atten_t, aux_t, X, out);
    } else {
        const size_t n4 = (size_t)N_ENT * K_DIM / 4;
        size_t stride = (size_t)CONV_BLKS * 256;
        for (size_t v = (size_t)(blockIdx.x - PREP_BLKS) * 256 + threadIdx.x; v < n4; v += stride) {
            float4 f = ((const float4*)ent)[v];
            ushort4 u;
            u.x = f2bf(f.x); u.y = f2bf(f.y); u.z = f2bf(f.z); u.w = f2bf(f.w);
            ((ushort4*)Eb)[v] = u;
        }
    }
}

// Standalone prep (fallback path only).
__global__ __launch_bounds__(64) void prep_kernel(
    const int* __restrict__ q, const float* __restrict__ ent,
    const float* __restrict__ rrot_t, const float* __restrict__ rboost_t,
    const float* __restrict__ atten_t, const float* __restrict__ aux_t,
    unsigned short* __restrict__ X, float* __restrict__ out)
{
    prep_row(blockIdx.x, threadIdx.x, q, ent, rrot_t, rboost_t, atten_t, aux_t, X, out);
}

// ---------------------------------------------------------------------------
// L3-traffic-first MFMA GEMM (R8 post-mortem: all prior variants staged
// 819 MB of E through L3 (~18 TB/s aggregate demand > L3 service) -- the
// schedule was never the binding constraint, B-reuse is).
// Tile 1024(M) x 128(N), BK=32. B(E) sweeps: M_PAD/BM = 2 -> 410 MB L3.
// A(X) re-read 625x but X = 2.6 MB -> L2-resident (34.5 TB/s, headroom).
// 512 thr / 8 waves; wave w owns A-rows w*128..+127, all 128 N-cols:
// acc[8][8] floatx4 = 256 VGPR (+frags/addr ~340 total; <=450 no-spill;
// 2 waves/SIMD: 2x350 < 2048 VGPR/SIMD -- launch_bounds(512,1)).
// LDS: dbuf 2 x (A 64 KB + B 8 KB) = 144 KB. One barrier per K-tile
// (R3-proven): {ds_read 16 b128; stage t+1 (9 loads); lgkm0; 64 MFMA
// (setprio); vmcnt0; s_barrier} -- loads overlap the ~2000-cy MFMA burst.
// stage() takes the LDS *offset* (R5 lesson). Swizzle slot^=(row>>1)&3,
// key reduces to (fr>>1)&3 on read / (srow>>1)&3 on stage -- verified
// consistent (16i, 128l, n0 multiples drop out mod 4).
// Grid 2x625 = 1250; 80000 = 625*128, 2048 = 2*1024 -> no tail clamps.
// ---------------------------------------------------------------------------
#define BUFO2 36864   // shorts per buffer (72 KB)

__global__ __launch_bounds__(512, 1) void gemm1024(
    const unsigned short* __restrict__ X,   // (2048, 640) bf16
    const unsigned short* __restrict__ Eb,  // (80000, 640) bf16
    float* __restrict__ C)
{
    __shared__ unsigned short lds[73728];   // 144 KB

    const int tid = threadIdx.x;
    const int lane = tid & 63;
    const int wid = tid >> 6;         // 0..7: wave owns A-rows wid*128..+127

    const int bid = blockIdx.x;
    const int m0 = (bid & 1) * 1024;
    const int n0 = (bid >> 1) * 128;

    const int fr = lane & 15;
    const int kq = lane >> 4;                     // 0..3
    const int cbs8 = (kq ^ ((fr >> 1) & 3)) * 8;  // swizzled 16B slot (shorts)

    floatx4 acc[8][8];
    #pragma unroll
    for (int i = 0; i < 8; i++)
        #pragma unroll
        for (int j = 0; j < 8; j++) acc[i][j] = (floatx4)0.0f;

    // ds_read offsets (shorts): A within [0,32768), B within [32768,36864)
    int aoff[8], boff[8];
    #pragma unroll
    for (int i = 0; i < 8; i++) aoff[i] = (wid * 128 + i * 16 + fr) * 32 + cbs8;
    #pragma unroll
    for (int j = 0; j < 8; j++) boff[j] = 32768 + (j * 16 + fr) * 32 + cbs8;

    // staging: thread -> (srow = tid>>2 in 0..127, slot = tid&3).
    // LDS dest linear (16B * tid per region); global k-slot pre-swizzled.
    const int srow = tid >> 2;
    const int scolg = ((tid & 3) ^ ((srow >> 1) & 3)) * 8;   // shorts

    auto stage = [&](int bufOff, int kt) {   // bufOff IS the short-offset (R5)
        #pragma unroll
        for (int l = 0; l < 8; l++) {
            const unsigned short* gp = X + (size_t)(m0 + l * 128 + srow) * K_DIM + kt * 32 + scolg;
            __builtin_amdgcn_global_load_lds((gu32*)gp,
                (lu32*)&lds[bufOff + l * 4096 + tid * 8], 16, 0, 0);
        }
        const unsigned short* gb = Eb + (size_t)(n0 + srow) * K_DIM + kt * 32 + scolg;
        __builtin_amdgcn_global_load_lds((gu32*)gb,
            (lu32*)&lds[bufOff + 32768 + tid * 8], 16, 0, 0);
    };

    // Prologue: tile 0, full drain (R4 rule: region-granular counting only).
    stage(0, 0);
    VMCNT0();
    __builtin_amdgcn_s_barrier();

    int bufo = 0;
    for (int t = 0; t < NT32; t++) {
        short8v a_[8], b_[8];
        #pragma unroll
        for (int i = 0; i < 8; i++) a_[i] = *(const short8v*)&lds[bufo + aoff[i]];
        #pragma unroll
        for (int j = 0; j < 8; j++) b_[j] = *(const short8v*)&lds[bufo + boff[j]];

        if (t < NT32 - 1) stage(bufo ^ BUFO2, t + 1);  // write OTHER buffer:
        // its last readers passed the previous barrier -> no WAR hazard.

        LGKM0();                               // ds_reads landed
        __builtin_amdgcn_sched_barrier(0);     // rule 18: pin MFMAs after wait
        __builtin_amdgcn_s_setprio(1);
        #pragma unroll
        for (int i = 0; i < 8; i++)
            #pragma unroll
            for (int j = 0; j < 8; j++)
                acc[i][j] = __builtin_amdgcn_mfma_f32_16x16x32_bf16(
                    a_[i], b_[j], acc[i][j], 0, 0, 0);
        __builtin_amdgcn_s_setprio(0);

        VMCNT0();                              // stage loads had full MFMA burst
        __builtin_amdgcn_s_barrier();
        bufo ^= BUFO2;
    }

    // Epilogue: C/D layout col=lane&15, row=(lane>>4)*4+reg (m89-verified).
    const int rb = kq * 4;
    #pragma unroll
    for (int i = 0; i < 8; i++) {
        int row = m0 + wid * 128 + i * 16 + rb;
        #pragma unroll
        for (int j = 0; j < 8; j++) {
            int col = n0 + j * 16 + fr;
            #pragma unroll
            for (int r = 0; r < 4; r++) {
                if (row + r < B_Q)
                    C[(size_t)(row + r) * N_ENT + col] = acc[i][j][r];
            }
        }
    }
}

// ---------------------------------------------------------------------------
// Fallback GEMM (R2-verified) for ws-too-small case.
// ---------------------------------------------------------------------------
__global__ __launch_bounds__(256) void gemm_mfma_fb(
    const unsigned short* __restrict__ X,
    const float* __restrict__ Ef,
    float* __restrict__ C)
{
    __shared__ unsigned short As[128 * 32];
    __shared__ unsigned short Bs[128 * 32];

    const int tid = threadIdx.x;
    const int lane = tid & 63;
    const int wave = tid >> 6;
    const int wm = wave >> 1, wn = wave & 1;
    const int m0 = blockIdx.x * 128;
    const int n0 = blockIdx.y * 128;

    floatx4 acc[4][4];
    #pragma unroll
    for (int i = 0; i < 4; i++)
        #pragma unroll
        for (int j = 0; j < 4; j++) acc[i][j] = (floatx4)0.0f;

    const int srow = tid >> 2;
    const int scol = (tid & 3) * 8;
    const int fr = lane & 15;
    const int kb = (lane >> 4) * 8;
    const int brow_f = tid >> 1;
    const int bcol_f = (tid & 1) * 16;

    for (int k0 = 0; k0 < K_DIM; k0 += 32) {
        __syncthreads();
        #pragma unroll
        for (int r = 0; r < 2; r++) {
            const unsigned short* gp = X + (size_t)(m0 + srow + r * 64) * K_DIM + k0 + scol;
            __builtin_amdgcn_global_load_lds((gu32*)gp, (lu32*)(As + (size_t)(r * 64 + srow) * 32 + scol), 16, 0, 0);
        }
        {
            const float* ep = Ef + (size_t)(n0 + brow_f) * K_DIM + k0 + bcol_f;
            float4 f0 = *(const float4*)(ep);
            float4 f1 = *(const float4*)(ep + 4);
            float4 f2 = *(const float4*)(ep + 8);
            float4 f3 = *(const float4*)(ep + 12);
            short8v p0, p1;
            p0[0] = (short)f2bf(f0.x); p0[1] = (short)f2bf(f0.y);
            p0[2] = (short)f2bf(f0.z); p0[3] = (short)f2bf(f0.w);
            p0[4] = (short)f2bf(f1.x); p0[5] = (short)f2bf(f1.y);
            p0[6] = (short)f2bf(f1.z); p0[7] = (short)f2bf(f1.w);
            p1[0] = (short)f2bf(f2.x); p1[1] = (short)f2bf(f2.y);
            p1[2] = (short)f2bf(f2.z); p1[3] = (short)f2bf(f2.w);
            p1[4] = (short)f2bf(f3.x); p1[5] = (short)f2bf(f3.y);
            p1[6] = (short)f2bf(f3.z); p1[7] = (short)f2bf(f3.w);
            *(short8v*)(Bs + (size_t)brow_f * 32 + bcol_f) = p0;
            *(short8v*)(Bs + (size_t)brow_f * 32 + bcol_f + 8) = p1;
        }
        __syncthreads();

        short8v a[4], b[4];
        #pragma unroll
        for (int i = 0; i < 4; i++)
            a[i] = *(const short8v*)(As + (size_t)(wm * 64 + i * 16 + fr) * 32 + kb);
        #pragma unroll
        for (int j = 0; j < 4; j++)
            b[j] = *(const short8v*)(Bs + (size_t)(wn * 64 + j * 16 + fr) * 32 + kb);

        #pragma unroll
        for (int i = 0; i < 4; i++)
            #pragma unroll
            for (int j = 0; j < 4; j++)
                acc[i][j] = __builtin_amdgcn_mfma_f32_16x16x32_bf16(a[i], b[j], acc[i][j], 0, 0, 0);
    }

    const int rbase = (lane >> 4) * 4;
    #pragma unroll
    for (int i = 0; i < 4; i++) {
        #pragma unroll
        for (int j = 0; j < 4; j++) {
            int row = m0 + wm * 64 + i * 16 + rbase;
            int col = n0 + wn * 64 + j * 16 + fr;
            #pragma unroll
            for (int r = 0; r < 4; r++) {
                if (row + r < B_Q)
                    C[(size_t)(row + r) * N_ENT + col] = acc[i][j][r];
            }
        }
    }
}

extern "C" void kernel_launch(void* const* d_in, const int* in_sizes, int n_in,
                              void* d_out, int out_size, void* d_ws, size_t ws_size,
                              hipStream_t stream) {
    const int* queries = (const int*)d_in[0];
    const float* ent = (const float*)d_in[1];
    const float* rrot = (const float*)d_in[2];
    const float* rboost = (const float*)d_in[3];
    const float* atten = (const float*)d_in[4];
    const float* aux = (const float*)d_in[5];
    float* out = (float*)d_out;

    unsigned short* X = (unsigned short*)d_ws;            // 2048*640*2 = 2.62 MB
    const size_t offE = (size_t)M_PAD * K_DIM * 2;
    const size_t needE = (size_t)N_ENT * K_DIM * 2;       // 102.4 MB
    unsigned short* Eb = (unsigned short*)((char*)d_ws + offE);
    bool pre = (ws_size >= offE + needE);

    if (pre) {
        prepconv_kernel<<<PREP_BLKS + CONV_BLKS, 256, 0, stream>>>(
            queries, ent, rrot, rboost, atten, aux, X, Eb, out);
        gemm1024<<<2 * 625, 512, 0, stream>>>(X, Eb, out + OFF_SCORES);
    } else {
        prep_kernel<<<M_PAD, 64, 0, stream>>>(queries, ent, rrot, rboost, atten, aux, X, out);
        dim3 grid(M_PAD / 128, N_ENT / 128);
        gemm_mfma_fb<<<grid, 256, 0, stream>>>(X, ent, out + OFF_SCORES);
    }
}

// Round 10
// 390.682 us; speedup vs baseline: 4.4813x; 4.4813x over previous
//
#include <hip/hip_runtime.h>
#include <math.h>

#define RANK 64
#define D_DIM 320          // ENT_COMPS * RANK
#define K_DIM 640          // 2 * D_DIM
#define N_ENT 80000
#define B_Q 2000
#define M_PAD 2048         // B_Q padded (zero rows 2000..2047)
#define NBLK_N 313         // ceil(80000/256)
#define NT32 20            // K_DIM / 32
#define SCALE_F 0.125f     // 1/sqrt(64)
#define EPS_F 1e-9f

// d_out layout (floats)
#define OFF_SCORES 0ull
#define OFF_REG0 160000000ull
#define OFF_REG1 160640000ull
#define OFF_REG2 161280000ull
#define OFF_REG3 161920000ull
#define OFF_REG4 162048000ull

typedef __attribute__((ext_vector_type(8))) short short8v;   // 8 bf16 (4 VGPRs)
typedef __attribute__((ext_vector_type(4))) float floatx4;

typedef __attribute__((address_space(1))) const unsigned int gu32;
typedef __attribute__((address_space(3))) unsigned int lu32;

#define VMCNT8() asm volatile("s_waitcnt vmcnt(8)" ::: "memory")
#define VMCNT4() asm volatile("s_waitcnt vmcnt(4)" ::: "memory")
#define VMCNT0() asm volatile("s_waitcnt vmcnt(0)" ::: "memory")
#define LGKM0()  asm volatile("s_waitcnt lgkmcnt(0)" ::: "memory")

static __device__ __forceinline__ unsigned short f2bf(float f) {
    union { float f; unsigned int u; } a; a.f = f;
    unsigned int u = a.u;
    u += 0x7FFFu + ((u >> 16) & 1u);   // RNE (finite inputs only)
    return (unsigned short)(u >> 16);
}

// ---------------------------------------------------------------------------
// Prep body: query row b, lane 0..63. Writes X row (bf16) + reg outputs.
// ---------------------------------------------------------------------------
static __device__ __forceinline__ void prep_row(
    int b, int lane,
    const int* __restrict__ q,
    const float* __restrict__ ent,
    const float* __restrict__ rrot_t,
    const float* __restrict__ rboost_t,
    const float* __restrict__ atten_t,
    const float* __restrict__ aux_t,
    unsigned short* __restrict__ X,
    float* __restrict__ out)
{
    unsigned short* Xrow = X + (size_t)b * K_DIM;

    if (b >= B_Q) {  // zero pad rows so MFMA tiles read clean zeros
        #pragma unroll
        for (int c = 0; c < 10; c++) Xrow[lane * 10 + c] = 0;
        return;
    }

    int h = q[3 * b + 0];
    int r = q[3 * b + 1];
    int t = q[3 * b + 2];

    const float* eh = ent + (size_t)h * K_DIM;
    const float* et = ent + (size_t)t * K_DIM;

    float4 rv = *(const float4*)(rrot_t + (size_t)r * 256 + lane * 4);
    float4 bv = *(const float4*)(rboost_t + (size_t)r * 256 + lane * 4);

    const float* xr = eh + lane * 5;
    float x0 = xr[0], x1 = xr[1], x2 = xr[2], x3 = xr[3], x4 = xr[4];

    float rr2 = rv.x * rv.x + rv.y * rv.y + rv.z * rv.z + rv.w * rv.w;
    float rb2 = bv.x * bv.x + bv.y * bv.y + bv.z * bv.z + bv.w * bv.w;

    // rotate
    float qinv = 1.0f / sqrtf(rr2 + EPS_F);
    float qw = rv.x * qinv, qx = rv.y * qinv, qy = rv.z * qinv, qz = rv.w * qinv;
    float pw = x1, px = x2, py = x3, pz = x4;
    float rot[5];
    rot[0] = x0;
    rot[1] = qw * pw - qx * px - qy * py - qz * pz;
    rot[2] = qw * px + qx * pw + qy * pz - qz * py;
    rot[3] = qw * py - qx * pz + qy * pw + qz * px;
    rot[4] = qw * pz + qx * py - qy * px + qz * pw;

    // boost
    float vn2 = fminf(fmaxf(rb2, 0.0f), 0.999f);
    float sq = sqrtf(1.0f - vn2);
    float gamma = 1.0f / sq;
    float gm1 = vn2 / (sq * (1.0f + sq));  // gamma-1 without cancellation
    float vs = bv.x * x1 + bv.y * x2 + bv.z * x3 + bv.w * x4;
    float boo[5];
    boo[0] = gamma * (x0 + vs);
    float coef = gamma * x0 + gm1 * vs / (vn2 + EPS_F);
    boo[1] = x1 + coef * bv.x;
    boo[2] = x2 + coef * bv.y;
    boo[3] = x3 + coef * bv.z;
    boo[4] = x4 + coef * bv.w;

    // attention
    const float* at = atten_t + (size_t)r * D_DIM + lane * 5;
    float w0 = at[0] * rot[0] + at[1] * rot[1] + at[2] * rot[2] + at[3] * rot[3] + at[4] * rot[4];
    float w1 = at[0] * boo[0] + at[1] * boo[1] + at[2] * boo[2] + at[3] * boo[3] + at[4] * boo[4];
    #pragma unroll
    for (int off = 32; off; off >>= 1) {
        w0 += __shfl_xor(w0, off);
        w1 += __shfl_xor(w1, off);
    }
    w0 *= SCALE_F;
    w1 *= SCALE_F;
    float mx = fmaxf(w0, w1);
    float e0 = expf(w0 - mx), e1 = expf(w1 - mx);
    float inv = 1.0f / (e0 + e1);
    float wt0 = e0 * inv, wt1 = e1 * inv;

    const float* a0p = aux_t + (size_t)r * 640 + lane * 5;
    const float* a1p = a0p + D_DIM;
    float xre[5] = {x0, x1, x2, x3, x4};

    #pragma unroll
    for (int c = 0; c < 5; c++) {
        int d = lane * 5 + c;
        float lhs = wt0 * rot[c] + wt1 * boo[c];
        float im = eh[D_DIM + d];
        float a0 = a0p[c], a1 = a1p[c];
        Xrow[d]         = f2bf(lhs * a0 - im * a1);
        Xrow[D_DIM + d] = f2bf(lhs * a1 + im * a0);
        out[OFF_REG0 + (size_t)b * D_DIM + d] = sqrtf(xre[c] * xre[c] + im * im);
        out[OFF_REG1 + (size_t)b * D_DIM + d] = sqrtf(a0 * a0 + a1 * a1);
        float tre = et[d], tim = et[D_DIM + d];
        out[OFF_REG2 + (size_t)b * D_DIM + d] = sqrtf(tre * tre + tim * tim) * (1.0f / 3.0f);
    }
    out[OFF_REG3 + (size_t)b * RANK + lane] = sqrtf(rr2);
    out[OFF_REG4 + (size_t)b * RANK + lane] = sqrtf(rb2);
}

// ---------------------------------------------------------------------------
// Fused prep + E conversion (R7/R8-verified).
// ---------------------------------------------------------------------------
#define PREP_BLKS 512
#define CONV_BLKS 2048
__global__ __launch_bounds__(256) void prepconv_kernel(
    const int* __restrict__ q,
    const float* __restrict__ ent,
    const float* __restrict__ rrot_t,
    const float* __restrict__ rboost_t,
    const float* __restrict__ atten_t,
    const float* __restrict__ aux_t,
    unsigned short* __restrict__ X,
    unsigned short* __restrict__ Eb,
    float* __restrict__ out)
{
    if (blockIdx.x < PREP_BLKS) {
        int b = blockIdx.x * 4 + (threadIdx.x >> 6);   // 0..2047
        prep_row(b, threadIdx.x & 63, q, ent, rrot_t, rboost_t, atten_t, aux_t, X, out);
    } else {
        const size_t n4 = (size_t)N_ENT * K_DIM / 4;
        size_t stride = (size_t)CONV_BLKS * 256;
        for (size_t v = (size_t)(blockIdx.x - PREP_BLKS) * 256 + threadIdx.x; v < n4; v += stride) {
            float4 f = ((const float4*)ent)[v];
            ushort4 u;
            u.x = f2bf(f.x); u.y = f2bf(f.y); u.z = f2bf(f.z); u.w = f2bf(f.w);
            ((ushort4*)Eb)[v] = u;
        }
    }
}

// Standalone prep (fallback path only).
__global__ __launch_bounds__(64) void prep_kernel(
    const int* __restrict__ q, const float* __restrict__ ent,
    const float* __restrict__ rrot_t, const float* __restrict__ rboost_t,
    const float* __restrict__ atten_t, const float* __restrict__ aux_t,
    unsigned short* __restrict__ X, float* __restrict__ out)
{
    prep_row(blockIdx.x, threadIdx.x, q, ent, rrot_t, rboost_t, atten_t, aux_t, X, out);
}

// ---------------------------------------------------------------------------
// Depth-3-prefetch MFMA GEMM (R9 post-mortem: R3's 683 TF = the 2-phase
// ceiling; its cause is the per-tile vmcnt(0) drain -- loads get ~620 cy of
// MFMA cover vs ~900 cy HBM/L3 latency. Fix = T4's actual content: never
// drain to 0; deepen prefetch until cover >= latency.)
// Tile 256x256, BK=32, 512 thr / 8 waves (2M x 4N, per-wave 128x64,
// acc[8][4] = 128 VGPR -> ~220 total, no spill at any plausible cap;
// plain launch_bounds(512), NO 2nd arg (R9: occupancy hint caused 128-cap
// + acc spill -> 4.5 GB scratch traffic)).
// LDS: 4 buffers x 32 KB (A 16 KB + B 16 KB) = 128 KB. One barrier/K-tile.
// Iter t: {12 ds_read buf[t&3]; stage(t+3); vmcnt(8); lgkm0; sched_barrier;
// 32 MFMA (setprio); s_barrier}. Steady state: entry outstanding = t+1,t+2
// (8 loads); after stage 12; vmcnt(8) drains t+1 (issued 2 tiles ago,
// ~2500 cy cover). Prologue: stage 0,1,2 + FULL drain (R4 rule; also makes
// iters 0-2's vmcnt(8) trivially safe). Tail t=17: vmcnt(4); t=18: vmcnt(0);
// t=19: none. WAR (1 barrier): stage at t targets buf[(t-1)&3]; its readers'
// ds_reads completed before their iter-(t-1) lgkm0 < barrier. Verified.
// Swizzle slot^=(row>>1)&3 (R8/R9 field-verified pair). C stored nontemporal
// (keep L2 for E).
// ---------------------------------------------------------------------------
#define BUFSZ 16384   // shorts per buffer (32 KB): A [0,8192), B [8192,16384)

__global__ __launch_bounds__(512) void gemm256c(
    const unsigned short* __restrict__ X,   // (2048, 640) bf16
    const unsigned short* __restrict__ Eb,  // (80000, 640) bf16
    float* __restrict__ C)
{
    __shared__ unsigned short lds[4 * BUFSZ];   // 128 KB

    const int tid = threadIdx.x;
    const int lane = tid & 63;
    const int wid = tid >> 6;
    const int wm = wid >> 2;          // 0..1  (128-row half of M)
    const int wn = wid & 3;           // 0..3  (64-col quarter of N)

    const int bid = blockIdx.x;
    const int m0 = (bid & 7) * 256;        // m-panel == XCD id
    const int n0 = (bid >> 3) * 256;

    const int fr = lane & 15;
    const int kq = lane >> 4;                     // 0..3
    const int cbs8 = (kq ^ ((fr >> 1) & 3)) * 8;  // swizzled 16B slot (shorts)

    floatx4 acc[8][4];
    #pragma unroll
    for (int i = 0; i < 8; i++)
        #pragma unroll
        for (int j = 0; j < 4; j++) acc[i][j] = (floatx4)0.0f;

    int aoff[8], boff[4];
    #pragma unroll
    for (int i = 0; i < 8; i++) aoff[i] = (wm * 128 + i * 16 + fr) * 32 + cbs8;
    #pragma unroll
    for (int j = 0; j < 4; j++) boff[j] = 8192 + (wn * 64 + j * 16 + fr) * 32 + cbs8;

    // staging: thread -> (srow = tid>>2 in 0..127, slot = tid&3); LDS dest
    // linear (tid*8 shorts per region); global k-slot pre-swizzled.
    const int srow = tid >> 2;
    const int scolg = ((tid & 3) ^ ((srow >> 1) & 3)) * 8;   // shorts

    auto stage = [&](int bufBase /*short offset*/, int kt) {
        #pragma unroll
        for (int l = 0; l < 2; l++) {
            const unsigned short* ga = X + (size_t)(m0 + l * 128 + srow) * K_DIM + kt * 32 + scolg;
            __builtin_amdgcn_global_load_lds((gu32*)ga,
                (lu32*)&lds[bufBase + l * 4096 + tid * 8], 16, 0, 0);
        }
        #pragma unroll
        for (int l = 0; l < 2; l++) {
            int grow = n0 + l * 128 + srow;
            if (grow > N_ENT - 1) grow = N_ENT - 1;  // tail clamp (finite, never stored)
            const unsigned short* gb = Eb + (size_t)grow * K_DIM + kt * 32 + scolg;
            __builtin_amdgcn_global_load_lds((gu32*)gb,
                (lu32*)&lds[bufBase + 8192 + l * 4096 + tid * 8], 16, 0, 0);
        }
    };

#define KSTEP(BUFB, STAGE_STMT, WAIT_STMT)                                    \
    {                                                                         \
        short8v a_[8], b_[4];                                                 \
        _Pragma("unroll")                                                     \
        for (int i = 0; i < 8; i++) a_[i] = *(const short8v*)&lds[(BUFB) + aoff[i]]; \
        _Pragma("unroll")                                                     \
        for (int j = 0; j < 4; j++) b_[j] = *(const short8v*)&lds[(BUFB) + boff[j]]; \
        STAGE_STMT;                                                           \
        WAIT_STMT;                                                            \
        LGKM0();                                                              \
        __builtin_amdgcn_sched_barrier(0);                                    \
        __builtin_amdgcn_s_setprio(1);                                        \
        _Pragma("unroll")                                                     \
        for (int i = 0; i < 8; i++)                                           \
            _Pragma("unroll")                                                 \
            for (int j = 0; j < 4; j++)                                       \
                acc[i][j] = __builtin_amdgcn_mfma_f32_16x16x32_bf16(          \
                    a_[i], b_[j], acc[i][j], 0, 0, 0);                        \
        __builtin_amdgcn_s_setprio(0);                                        \
        __builtin_amdgcn_s_barrier();                                         \
    }

    // Prologue: tiles 0..2 staged, FULL drain (sound at region granularity;
    // converges to the steady-state invariant by iter 3 -- each early
    // vmcnt(8) is then a no-op on already-drained buffers).
    stage(0 * BUFSZ, 0);
    stage(1 * BUFSZ, 1);
    stage(2 * BUFSZ, 2);
    VMCNT0();
    __builtin_amdgcn_s_barrier();

    for (int t = 0; t < NT32 - 3; t++) {     // t = 0..16
        const int bufb = (t & 3) * BUFSZ;
        const int stgb = ((t + 3) & 3) * BUFSZ;
        KSTEP(bufb, stage(stgb, t + 3), VMCNT8())
    }
    KSTEP((17 & 3) * BUFSZ, (void)0, VMCNT4())   // t=17: drain tile 18
    KSTEP((18 & 3) * BUFSZ, (void)0, VMCNT0())   // t=18: drain tile 19
    KSTEP((19 & 3) * BUFSZ, (void)0, (void)0)    // t=19: nothing outstanding
#undef KSTEP

    // Epilogue: C/D layout col=lane&15, row=(lane>>4)*4+reg (m89-verified).
    // Non-temporal stores: C is write-once, keep L2 for E.
    const int rb = kq * 4;
    #pragma unroll
    for (int i = 0; i < 8; i++) {
        int row = m0 + wm * 128 + i * 16 + rb;
        #pragma unroll
        for (int j = 0; j < 4; j++) {
            int col = n0 + wn * 64 + j * 16 + fr;
            if (col < N_ENT) {
                #pragma unroll
                for (int r = 0; r < 4; r++) {
                    if (row + r < B_Q)
                        __builtin_nontemporal_store(acc[i][j][r],
                            &C[(size_t)(row + r) * N_ENT + col]);
                }
            }
        }
    }
}

// ---------------------------------------------------------------------------
// Fallback GEMM (R2-verified) for ws-too-small case.
// ---------------------------------------------------------------------------
__global__ __launch_bounds__(256) void gemm_mfma_fb(
    const unsigned short* __restrict__ X,
    const float* __restrict__ Ef,
    float* __restrict__ C)
{
    __shared__ unsigned short As[128 * 32];
    __shared__ unsigned short Bs[128 * 32];

    const int tid = threadIdx.x;
    const int lane = tid & 63;
    const int wave = tid >> 6;
    const int wm = wave >> 1, wn = wave & 1;
    const int m0 = blockIdx.x * 128;
    const int n0 = blockIdx.y * 128;

    floatx4 acc[4][4];
    #pragma unroll
    for (int i = 0; i < 4; i++)
        #pragma unroll
        for (int j = 0; j < 4; j++) acc[i][j] = (floatx4)0.0f;

    const int srow = tid >> 2;
    const int scol = (tid & 3) * 8;
    const int fr = lane & 15;
    const int kb = (lane >> 4) * 8;
    const int brow_f = tid >> 1;
    const int bcol_f = (tid & 1) * 16;

    for (int k0 = 0; k0 < K_DIM; k0 += 32) {
        __syncthreads();
        #pragma unroll
        for (int r = 0; r < 2; r++) {
            const unsigned short* gp = X + (size_t)(m0 + srow + r * 64) * K_DIM + k0 + scol;
            __builtin_amdgcn_global_load_lds((gu32*)gp, (lu32*)(As + (size_t)(r * 64 + srow) * 32 + scol), 16, 0, 0);
        }
        {
            const float* ep = Ef + (size_t)(n0 + brow_f) * K_DIM + k0 + bcol_f;
            float4 f0 = *(const float4*)(ep);
            float4 f1 = *(const float4*)(ep + 4);
            float4 f2 = *(const float4*)(ep + 8);
            float4 f3 = *(const float4*)(ep + 12);
            short8v p0, p1;
            p0[0] = (short)f2bf(f0.x); p0[1] = (short)f2bf(f0.y);
            p0[2] = (short)f2bf(f0.z); p0[3] = (short)f2bf(f0.w);
            p0[4] = (short)f2bf(f1.x); p0[5] = (short)f2bf(f1.y);
            p0[6] = (short)f2bf(f1.z); p0[7] = (short)f2bf(f1.w);
            p1[0] = (short)f2bf(f2.x); p1[1] = (short)f2bf(f2.y);
            p1[2] = (short)f2bf(f2.z); p1[3] = (short)f2bf(f2.w);
            p1[4] = (short)f2bf(f3.x); p1[5] = (short)f2bf(f3.y);
            p1[6] = (short)f2bf(f3.z); p1[7] = (short)f2bf(f3.w);
            *(short8v*)(Bs + (size_t)brow_f * 32 + bcol_f) = p0;
            *(short8v*)(Bs + (size_t)brow_f * 32 + bcol_f + 8) = p1;
        }
        __syncthreads();

        short8v a[4], b[4];
        #pragma unroll
        for (int i = 0; i < 4; i++)
            a[i] = *(const short8v*)(As + (size_t)(wm * 64 + i * 16 + fr) * 32 + kb);
        #pragma unroll
        for (int j = 0; j < 4; j++)
            b[j] = *(const short8v*)(Bs + (size_t)(wn * 64 + j * 16 + fr) * 32 + kb);

        #pragma unroll
        for (int i = 0; i < 4; i++)
            #pragma unroll
            for (int j = 0; j < 4; j++)
                acc[i][j] = __builtin_amdgcn_mfma_f32_16x16x32_bf16(a[i], b[j], acc[i][j], 0, 0, 0);
    }

    const int rbase = (lane >> 4) * 4;
    #pragma unroll
    for (int i = 0; i < 4; i++) {
        #pragma unroll
        for (int j = 0; j < 4; j++) {
            int row = m0 + wm * 64 + i * 16 + rbase;
            int col = n0 + wn * 64 + j * 16 + fr;
            #pragma unroll
            for (int r = 0; r < 4; r++) {
                if (row + r < B_Q)
                    C[(size_t)(row + r) * N_ENT + col] = acc[i][j][r];
            }
        }
    }
}

extern "C" void kernel_launch(void* const* d_in, const int* in_sizes, int n_in,
                              void* d_out, int out_size, void* d_ws, size_t ws_size,
                              hipStream_t stream) {
    const int* queries = (const int*)d_in[0];
    const float* ent = (const float*)d_in[1];
    const float* rrot = (const float*)d_in[2];
    const float* rboost = (const float*)d_in[3];
    const float* atten = (const float*)d_in[4];
    const float* aux = (const float*)d_in[5];
    float* out = (float*)d_out;

    unsigned short* X = (unsigned short*)d_ws;            // 2048*640*2 = 2.62 MB
    const size_t offE = (size_t)M_PAD * K_DIM * 2;
    const size_t needE = (size_t)N_ENT * K_DIM * 2;       // 102.4 MB
    unsigned short* Eb = (unsigned short*)((char*)d_ws + offE);
    bool pre = (ws_size >= offE + needE);

    if (pre) {
        prepconv_kernel<<<PREP_BLKS + CONV_BLKS, 256, 0, stream>>>(
            queries, ent, rrot, rboost, atten, aux, X, Eb, out);
        gemm256c<<<8 * NBLK_N, 512, 0, stream>>>(X, Eb, out + OFF_SCORES);
    } else {
        prep_kernel<<<M_PAD, 64, 0, stream>>>(queries, ent, rrot, rboost, atten, aux, X, out);
        dim3 grid(M_PAD / 128, N_ENT / 128);
        gemm_mfma_fb<<<grid, 256, 0, stream>>>(X, ent, out + OFF_SCORES);
    }
}